// Round 1
// baseline (7062.271 us; speedup 1.0000x reference)
//
#include <hip/hip_runtime.h>

// GNN MixHopConv: 8 sequential sparse props on [N,2] fp32 features.
// Edge pass reads only (src,dst); weights folded into node-side scaling:
//   prop(x)[i] = dis[i] * sum_{e:dst=i} (dis[src]*x[src]) + dis[i]^2 * x[i]
// so we scatter xs[src] where xs = dis*x (no per-edge weight gather).

constexpr int NN = 500000;
constexpr int NE = 8000000;
constexpr int STEP_DIM = 8;
constexpr int HIDM1 = 7;
constexpr int BLK = 256;

__global__ __launch_bounds__(256) void k_deg(const int* __restrict__ dst,
                                             int* __restrict__ deg) {
  int t = blockIdx.x * blockDim.x + threadIdx.x;
  if (t * 4 >= NE) return;
  int4 d4 = ((const int4*)dst)[t];
  atomicAdd(&deg[d4.x], 1);
  atomicAdd(&deg[d4.y], 1);
  atomicAdd(&deg[d4.z], 1);
  atomicAdd(&deg[d4.w], 1);
}

// dis[i] = 1/sqrt(deg+1); xs = dis*X; re-zero the deg buffer (it becomes accD).
__global__ __launch_bounds__(256) void k_node_init(int* __restrict__ degaccd,
                                                   const float2* __restrict__ X,
                                                   float* __restrict__ dis,
                                                   float2* __restrict__ xs) {
  int i = blockIdx.x * blockDim.x + threadIdx.x;
  if (i >= NN) return;
  float d = 1.0f / sqrtf((float)degaccd[i] + 1.0f);
  dis[i] = d;
  float2 x = X[i];
  xs[i] = make_float2(d * x.x, d * x.y);
  ((float*)degaccd)[i] = 0.0f;  // buffer reused as accD for layer 0
}

// Layer-0 edge pass: scatter xs[src] (features) and dis[src] (for rowsum).
__global__ __launch_bounds__(256) void k_edge0(const int* __restrict__ src,
                                               const int* __restrict__ dst,
                                               const float2* __restrict__ xs,
                                               const float* __restrict__ dis,
                                               float* __restrict__ accA,
                                               float* __restrict__ accD) {
  int t = blockIdx.x * blockDim.x + threadIdx.x;
  if (t * 4 >= NE) return;
  int4 s4 = ((const int4*)src)[t];
  int4 d4 = ((const int4*)dst)[t];
  int ss[4] = {s4.x, s4.y, s4.z, s4.w};
  int dd[4] = {d4.x, d4.y, d4.z, d4.w};
#pragma unroll
  for (int j = 0; j < 4; ++j) {
    float2 v = xs[ss[j]];
    float ds = dis[ss[j]];
    unsafeAtomicAdd(&accA[2 * dd[j] + 0], v.x);
    unsafeAtomicAdd(&accA[2 * dd[j] + 1], v.y);
    unsafeAtomicAdd(&accD[dd[j]], ds);
  }
}

// Generic edge pass (layers 1..7): scatter xs[src] only.
__global__ __launch_bounds__(256) void k_edge(const int* __restrict__ src,
                                              const int* __restrict__ dst,
                                              const float2* __restrict__ xs,
                                              float* __restrict__ accA) {
  int t = blockIdx.x * blockDim.x + threadIdx.x;
  if (t * 4 >= NE) return;
  int4 s4 = ((const int4*)src)[t];
  int4 d4 = ((const int4*)dst)[t];
  int ss[4] = {s4.x, s4.y, s4.z, s4.w};
  int dd[4] = {d4.x, d4.y, d4.z, d4.w};
#pragma unroll
  for (int j = 0; j < 4; ++j) {
    float2 v = xs[ss[j]];
    unsafeAtomicAdd(&accA[2 * dd[j] + 0], v.x);
    unsafeAtomicAdd(&accA[2 * dd[j] + 1], v.y);
  }
}

// Layer-0 node update. x_cat = [X, s] with s = step_emb[step_index] constant
// across nodes, so prop of the s-columns = rowsum[i]*s.
// h = X@W00[0:2] + s@W00[2:10] + b00 + p@W01[0:2] + rowsum*(s@W01[2:10]) + b01
__global__ __launch_bounds__(256) void k_node0(const float2* __restrict__ X,
                                               const float* __restrict__ dis,
                                               float2* __restrict__ accA,
                                               const float* __restrict__ accD,
                                               const float* __restrict__ W0,
                                               const float* __restrict__ b0,
                                               const float* __restrict__ step_emb,
                                               const int* __restrict__ step_index,
                                               float2* __restrict__ xbuf,
                                               float2* __restrict__ xs) {
  int i = blockIdx.x * blockDim.x + threadIdx.x;
  if (i >= NN) return;
  // Uniform constants (scalar loads / broadcast — negligible traffic).
  const float* s = step_emb + step_index[0] * STEP_DIM;
  float c0[2], c1[2];
#pragma unroll
  for (int o = 0; o < 2; ++o) {
    float a0 = b0[o] + b0[2 + o];  // b0[0][o] + b0[1][o]
    float a1 = 0.f;
#pragma unroll
    for (int j = 0; j < STEP_DIM; ++j) {
      a0 += s[j] * W0[(2 + j) * 2 + o];        // W0[0][2+j][o]
      a1 += s[j] * W0[20 + (2 + j) * 2 + o];   // W0[1][2+j][o]
    }
    c0[o] = a0;
    c1[o] = a1;
  }
  float d = dis[i], d2 = d * d;
  float2 x = X[i];
  float2 a = accA[i];
  float rowsum = d * accD[i] + d2;
  float px = d * a.x + d2 * x.x;
  float py = d * a.y + d2 * x.y;
  float h0 = c0[0] + rowsum * c1[0] + x.x * W0[0] + x.y * W0[2] + px * W0[20] + py * W0[22];
  float h1 = c0[1] + rowsum * c1[1] + x.x * W0[1] + x.y * W0[3] + px * W0[21] + py * W0[23];
  float2 xn = make_float2(fmaxf(h0, 0.f), fmaxf(h1, 0.f));
  xbuf[i] = xn;
  xs[i] = make_float2(d * xn.x, d * xn.y);
  accA[i] = make_float2(0.f, 0.f);  // reset accumulator for next layer
}

// Layers 1..7 node update. W: [K=2][C=2][C=2] -> W[k*4+in*2+o]; b: [2][2].
__global__ __launch_bounds__(256) void k_node(float2* __restrict__ xbuf,
                                              const float* __restrict__ dis,
                                              float2* __restrict__ accA,
                                              const float* __restrict__ W,
                                              const float* __restrict__ b,
                                              float2* __restrict__ xs,
                                              float2* __restrict__ out,
                                              int last) {
  int i = blockIdx.x * blockDim.x + threadIdx.x;
  if (i >= NN) return;
  float d = dis[i], d2 = d * d;
  float2 x = xbuf[i];
  float2 a = accA[i];
  float px = d * a.x + d2 * x.x;
  float py = d * a.y + d2 * x.y;
  float h0 = b[0] + b[2] + x.x * W[0] + x.y * W[2] + px * W[4] + py * W[6];
  float h1 = b[1] + b[3] + x.x * W[1] + x.y * W[3] + px * W[5] + py * W[7];
  float2 xn = make_float2(fmaxf(h0, 0.f), fmaxf(h1, 0.f));
  if (last) {
    out[i] = xn;
  } else {
    xbuf[i] = xn;
    xs[i] = make_float2(d * xn.x, d * xn.y);
    accA[i] = make_float2(0.f, 0.f);
  }
}

extern "C" void kernel_launch(void* const* d_in, const int* in_sizes, int n_in,
                              void* d_out, int out_size, void* d_ws, size_t ws_size,
                              hipStream_t stream) {
  const float2* X        = (const float2*)d_in[0];
  const int*    edge     = (const int*)d_in[1];
  const int*    src      = edge;            // edge_index[0]
  const int*    dstp     = edge + NE;       // edge_index[1]
  const int*    step_idx = (const int*)d_in[2];
  const float*  step_emb = (const float*)d_in[3];
  const float*  W0       = (const float*)d_in[4];
  const float*  b0       = (const float*)d_in[5];
  const float*  Wh       = (const float*)d_in[6];
  const float*  bh       = (const float*)d_in[7];

  // Workspace layout (floats): [deg/accD: N][accA: 2N][dis: N][xs: 2N][xbuf: 2N] = 8N = 16 MB
  float*  ws   = (float*)d_ws;
  int*    deg  = (int*)ws;                  // N (aliased with accD)
  float*  accD = ws;                        // N
  float*  accA = ws + NN;                   // 2N
  float*  dis  = ws + 3 * (size_t)NN;       // N
  float2* xs   = (float2*)(ws + 4 * (size_t)NN);  // 2N
  float2* xbuf = (float2*)(ws + 6 * (size_t)NN);  // 2N

  // Zero deg + accA (contiguous 3N floats). accD re-zeroed inside k_node_init.
  hipMemsetAsync(d_ws, 0, (size_t)3 * NN * sizeof(float), stream);

  int egrid = (NE / 4 + BLK - 1) / BLK;
  int ngrid = (NN + BLK - 1) / BLK;

  k_deg<<<egrid, BLK, 0, stream>>>(dstp, deg);
  k_node_init<<<ngrid, BLK, 0, stream>>>(deg, X, dis, xs);
  k_edge0<<<egrid, BLK, 0, stream>>>(src, dstp, xs, dis, accA, accD);
  k_node0<<<ngrid, BLK, 0, stream>>>(X, dis, (float2*)accA, accD, W0, b0,
                                     step_emb, step_idx, xbuf, xs);
  for (int l = 0; l < HIDM1; ++l) {
    k_edge<<<egrid, BLK, 0, stream>>>(src, dstp, xs, accA);
    k_node<<<ngrid, BLK, 0, stream>>>(xbuf, dis, (float2*)accA, Wh + l * 8,
                                      bh + l * 4, xs, (float2*)d_out,
                                      l == HIDM1 - 1 ? 1 : 0);
  }
}

// Round 2
// 1717.050 us; speedup vs baseline: 4.1130x; 4.1130x over previous
//
#include <hip/hip_runtime.h>

// MixHopConv, 8 sequential GCN props on [N,2] fp32.
// Round-1 lesson: device-scope atomics run at ~20 G op/s through the coherent
// fabric (WRITE_SIZE showed ~32 B/atomic to HBM). So: pay atomics ONCE to
// build a dst-CSR (counting sort), then every layer is an atomic-free
// gather-reduce fused with the 2x2 node update (register accumulation).
//
//   prop(x)[i] = dis[i]*sum_{e: dst=i} xs[src[e]] + dis[i]*xs[i],  xs = dis*x

constexpr int NN = 500000;
constexpr int NE = 8000000;
constexpr int STEP_DIM = 8;
constexpr int HIDM1 = 7;
constexpr int BLK = 256;
constexpr int CHUNK = 2048;                       // scan: 256 thr * 8 elems
constexpr int NB = (NN + CHUNK - 1) / CHUNK;      // 245 scan blocks

// ---- CSR build -------------------------------------------------------------

// rank[e] = arrival order of edge e at its dst; cnt[d] ends as in-degree.
__global__ __launch_bounds__(256) void k_rank(const int* __restrict__ dst,
                                              int* __restrict__ cnt,
                                              int* __restrict__ rank) {
  int t = blockIdx.x * blockDim.x + threadIdx.x;
  if (t * 4 >= NE) return;
  int4 d4 = ((const int4*)dst)[t];
  int r0 = atomicAdd(&cnt[d4.x], 1);
  int r1 = atomicAdd(&cnt[d4.y], 1);
  int r2 = atomicAdd(&cnt[d4.z], 1);
  int r3 = atomicAdd(&cnt[d4.w], 1);
  ((int4*)rank)[t] = make_int4(r0, r1, r2, r3);
}

// deg only (fallback path when ws is too small for the rank array).
__global__ __launch_bounds__(256) void k_deg(const int* __restrict__ dst,
                                             int* __restrict__ cnt) {
  int t = blockIdx.x * blockDim.x + threadIdx.x;
  if (t * 4 >= NE) return;
  int4 d4 = ((const int4*)dst)[t];
  atomicAdd(&cnt[d4.x], 1);
  atomicAdd(&cnt[d4.y], 1);
  atomicAdd(&cnt[d4.z], 1);
  atomicAdd(&cnt[d4.w], 1);
}

__global__ __launch_bounds__(256) void k_scan_partial(const int* __restrict__ cnt,
                                                      int* __restrict__ partials) {
  __shared__ int sm[BLK];
  int b = blockIdx.x, t = threadIdx.x;
  int base = b * CHUNK + t * 8;
  int s = 0;
#pragma unroll
  for (int j = 0; j < 8; ++j) {
    int i = base + j;
    s += (i < NN) ? cnt[i] : 0;
  }
  sm[t] = s;
  __syncthreads();
  for (int off = BLK / 2; off > 0; off >>= 1) {
    if (t < off) sm[t] += sm[t + off];
    __syncthreads();
  }
  if (t == 0) partials[b] = sm[0];
}

__global__ __launch_bounds__(256) void k_scan_mid(int* __restrict__ partials) {
  __shared__ int sm[BLK];
  int t = threadIdx.x;
  int v = (t < NB) ? partials[t] : 0;
  sm[t] = v;
  __syncthreads();
  for (int off = 1; off < BLK; off <<= 1) {
    int x = (t >= off) ? sm[t - off] : 0;
    __syncthreads();
    sm[t] += x;
    __syncthreads();
  }
  if (t < NB) partials[t] = sm[t] - v;  // exclusive prefix
}

__global__ __launch_bounds__(256) void k_scan_down(const int* __restrict__ cnt,
                                                   const int* __restrict__ partials,
                                                   int* __restrict__ rowstart) {
  __shared__ int sm[BLK];
  int b = blockIdx.x, t = threadIdx.x;
  int base = b * CHUNK + t * 8;
  int v[8];
  int s = 0;
#pragma unroll
  for (int j = 0; j < 8; ++j) {
    int i = base + j;
    v[j] = (i < NN) ? cnt[i] : 0;
    s += v[j];
  }
  sm[t] = s;
  __syncthreads();
  for (int off = 1; off < BLK; off <<= 1) {
    int x = (t >= off) ? sm[t - off] : 0;
    __syncthreads();
    sm[t] += x;
    __syncthreads();
  }
  int run = partials[b] + (sm[t] - s);
#pragma unroll
  for (int j = 0; j < 8; ++j) {
    int i = base + j;
    if (i < NN) rowstart[i] = run;
    run += v[j];
  }
  if (b == 0 && t == 0) rowstart[NN] = NE;
}

// Scatter with precomputed ranks — atomic-free.
__global__ __launch_bounds__(256) void k_scatter(const int* __restrict__ src,
                                                 const int* __restrict__ dst,
                                                 const int* __restrict__ rank,
                                                 const int* __restrict__ rowstart,
                                                 int* __restrict__ col) {
  int t = blockIdx.x * blockDim.x + threadIdx.x;
  if (t * 4 >= NE) return;
  int4 s4 = ((const int4*)src)[t];
  int4 d4 = ((const int4*)dst)[t];
  int4 r4 = ((const int4*)rank)[t];
  col[rowstart[d4.x] + r4.x] = s4.x;
  col[rowstart[d4.y] + r4.y] = s4.y;
  col[rowstart[d4.z] + r4.z] = s4.z;
  col[rowstart[d4.w] + r4.w] = s4.w;
}

// Scatter with cursor atomics (fallback when no rank array).
__global__ __launch_bounds__(256) void k_scatter_atomic(const int* __restrict__ src,
                                                        const int* __restrict__ dst,
                                                        int* __restrict__ cursor,
                                                        int* __restrict__ col) {
  int t = blockIdx.x * blockDim.x + threadIdx.x;
  if (t * 4 >= NE) return;
  int4 s4 = ((const int4*)src)[t];
  int4 d4 = ((const int4*)dst)[t];
  col[atomicAdd(&cursor[d4.x], 1)] = s4.x;
  col[atomicAdd(&cursor[d4.y], 1)] = s4.y;
  col[atomicAdd(&cursor[d4.z], 1)] = s4.z;
  col[atomicAdd(&cursor[d4.w], 1)] = s4.w;
}

// ---- node-side precompute --------------------------------------------------

// dis = 1/sqrt(deg+1); g0 = {dis*X.x, dis*X.y, dis, 0} (single float4 gather
// target for layer 0: features AND the rowsum term in one 16B load).
__global__ __launch_bounds__(256) void k_init(const float2* __restrict__ X,
                                              const int* __restrict__ cnt,
                                              float* __restrict__ dis,
                                              float4* __restrict__ g0) {
  int i = blockIdx.x * blockDim.x + threadIdx.x;
  if (i >= NN) return;
  float d = 1.0f / sqrtf((float)cnt[i] + 1.0f);
  dis[i] = d;
  float2 x = X[i];
  g0[i] = make_float4(d * x.x, d * x.y, d, 0.f);
}

// ---- fused layers (atomic-free gather + 2x2 dense + relu) ------------------

__global__ __launch_bounds__(256) void k_layer0(const int* __restrict__ rowstart,
                                                const int* __restrict__ col,
                                                const float4* __restrict__ g0,
                                                const float2* __restrict__ X,
                                                const float* __restrict__ dis,
                                                const float* __restrict__ W0,
                                                const float* __restrict__ b0,
                                                const float* __restrict__ step_emb,
                                                const int* __restrict__ step_index,
                                                float2* __restrict__ xs_out) {
  int i = blockIdx.x * blockDim.x + threadIdx.x;
  if (i >= NN) return;
  // Uniform constants: s = step_emb[step_index] folded through W0 columns 2..9.
  const float* s = step_emb + step_index[0] * STEP_DIM;
  float c0[2], c1[2];
#pragma unroll
  for (int o = 0; o < 2; ++o) {
    float a0 = b0[o] + b0[2 + o];
    float a1 = 0.f;
#pragma unroll
    for (int j = 0; j < STEP_DIM; ++j) {
      a0 += s[j] * W0[(2 + j) * 2 + o];
      a1 += s[j] * W0[20 + (2 + j) * 2 + o];
    }
    c0[o] = a0;
    c1[o] = a1;
  }
  int e0 = rowstart[i], e1 = rowstart[i + 1];
  float sx = 0.f, sy = 0.f, sd = 0.f;
  for (int e = e0; e < e1; ++e) {
    float4 g = g0[col[e]];
    sx += g.x;
    sy += g.y;
    sd += g.z;
  }
  float d = dis[i], d2 = d * d;
  float2 x = X[i];
  float px = d * sx + d2 * x.x;
  float py = d * sy + d2 * x.y;
  float rowsum = d * sd + d2;
  float h0 = c0[0] + rowsum * c1[0] + x.x * W0[0] + x.y * W0[2] + px * W0[20] + py * W0[22];
  float h1 = c0[1] + rowsum * c1[1] + x.x * W0[1] + x.y * W0[3] + px * W0[21] + py * W0[23];
  h0 = fmaxf(h0, 0.f);
  h1 = fmaxf(h1, 0.f);
  xs_out[i] = make_float2(d * h0, d * h1);
}

// Layers 1..7. xs holds dis*x; self term dis^2*x = dis*xs; x = xs/dis.
__global__ __launch_bounds__(256) void k_layer(const int* __restrict__ rowstart,
                                               const int* __restrict__ col,
                                               const float* __restrict__ dis,
                                               const float2* __restrict__ xs_in,
                                               const float* __restrict__ W,
                                               const float* __restrict__ b,
                                               float2* __restrict__ xs_out,
                                               float2* __restrict__ out,
                                               int last) {
  int i = blockIdx.x * blockDim.x + threadIdx.x;
  if (i >= NN) return;
  int e0 = rowstart[i], e1 = rowstart[i + 1];
  float sx = 0.f, sy = 0.f;
  for (int e = e0; e < e1; ++e) {
    float2 v = xs_in[col[e]];
    sx += v.x;
    sy += v.y;
  }
  float d = dis[i];
  float2 xsv = xs_in[i];
  float inv = 1.0f / d;  // = sqrt(deg+1)
  float xx = xsv.x * inv, xy = xsv.y * inv;
  float px = d * (sx + xsv.x);
  float py = d * (sy + xsv.y);
  float h0 = b[0] + b[2] + xx * W[0] + xy * W[2] + px * W[4] + py * W[6];
  float h1 = b[1] + b[3] + xx * W[1] + xy * W[3] + px * W[5] + py * W[7];
  h0 = fmaxf(h0, 0.f);
  h1 = fmaxf(h1, 0.f);
  if (last) {
    out[i] = make_float2(h0, h1);
  } else {
    xs_out[i] = make_float2(d * h0, d * h1);
  }
}

// ---- driver ----------------------------------------------------------------

extern "C" void kernel_launch(void* const* d_in, const int* in_sizes, int n_in,
                              void* d_out, int out_size, void* d_ws, size_t ws_size,
                              hipStream_t stream) {
  const float2* X        = (const float2*)d_in[0];
  const int*    edge     = (const int*)d_in[1];
  const int*    src      = edge;
  const int*    dstp     = edge + NE;
  const int*    step_idx = (const int*)d_in[2];
  const float*  step_emb = (const float*)d_in[3];
  const float*  W0       = (const float*)d_in[4];
  const float*  b0       = (const float*)d_in[5];
  const float*  Wh       = (const float*)d_in[6];
  const float*  bh       = (const float*)d_in[7];

  // Workspace layout (int-indexed from base):
  // [col: NE][rowstart: NN+1][cnt: NN (pad to +16)][partials: ~NB (pad to 512)]
  // [g0: 4*NN f][xsA: 2*NN f][xsB: 2*NN f][dis: NN f][rank: NE | cursor: NN]
  int* ip = (int*)d_ws;
  int* col      = ip;
  int* rowstart = ip + NE;
  int* cnt      = ip + NE + NN + 16;
  int* partials = ip + NE + 2 * NN + 32;
  size_t off2   = (size_t)NE + 2 * NN + 32 + 512;  // multiple of 4
  float4* g0  = (float4*)(ip + off2);
  float2* xsA = (float2*)(ip + off2 + 4 * (size_t)NN);
  float2* xsB = (float2*)(ip + off2 + 6 * (size_t)NN);
  float*  dis = (float*)(ip + off2 + 8 * (size_t)NN);
  int*    rank   = ip + off2 + 9 * (size_t)NN;   // NE ints (big path)
  int*    cursor = ip + off2 + 9 * (size_t)NN;   // NN ints (small path)

  size_t need_rank  = (off2 + 9 * (size_t)NN + (size_t)NE) * sizeof(int);
  bool   have_rank  = ws_size >= need_rank;

  hipMemsetAsync(cnt, 0, (size_t)NN * sizeof(int), stream);

  int egrid = (NE / 4 + BLK - 1) / BLK;
  int ngrid = (NN + BLK - 1) / BLK;

  if (have_rank) {
    k_rank<<<egrid, BLK, 0, stream>>>(dstp, cnt, rank);
  } else {
    k_deg<<<egrid, BLK, 0, stream>>>(dstp, cnt);
  }
  k_scan_partial<<<NB, BLK, 0, stream>>>(cnt, partials);
  k_scan_mid<<<1, BLK, 0, stream>>>(partials);
  k_scan_down<<<NB, BLK, 0, stream>>>(cnt, partials, rowstart);
  if (have_rank) {
    k_scatter<<<egrid, BLK, 0, stream>>>(src, dstp, rank, rowstart, col);
  } else {
    hipMemcpyAsync(cursor, rowstart, (size_t)NN * sizeof(int),
                   hipMemcpyDeviceToDevice, stream);
    k_scatter_atomic<<<egrid, BLK, 0, stream>>>(src, dstp, cursor, col);
  }
  k_init<<<ngrid, BLK, 0, stream>>>(X, cnt, dis, g0);

  k_layer0<<<ngrid, BLK, 0, stream>>>(rowstart, col, g0, X, dis, W0, b0,
                                      step_emb, step_idx, xsB);
  float2* cur = xsB;
  float2* nxt = xsA;
  for (int l = 0; l < HIDM1; ++l) {
    k_layer<<<ngrid, BLK, 0, stream>>>(rowstart, col, dis, cur, Wh + l * 8,
                                       bh + l * 4, nxt, (float2*)d_out,
                                       l == HIDM1 - 1 ? 1 : 0);
    float2* t = cur;
    cur = nxt;
    nxt = t;
  }
}

// Round 3
// 968.293 us; speedup vs baseline: 7.2935x; 1.7733x over previous
//
#include <hip/hip_runtime.h>

// MixHopConv, 8 GCN props on [N,2] fp32. Round-2 lesson: global atomics
// (~24 G op/s) and scattered 4B writes (16x line-RMW amplification) dominated.
// This version: two-level bucket sort (bucket = dst>>11, 245 buckets x 2048
// nodes). All histograms/cursors live in LDS; the permute writes contiguous
// per-(block,bucket) runs (L2-friendly). Layers accumulate into a 16 KB LDS
// tile via ds_add_f32 — zero global atomics anywhere.
// Edge packs to uint32: (local_dst<<19)|src  (N=500000 < 2^19).

constexpr int NN = 500000;
constexpr int NE = 8000000;
constexpr int STEP_DIM = 8;
constexpr int HIDM1 = 7;

constexpr int BSH  = 11;
constexpr int BNOD = 1 << BSH;                  // 2048 nodes / bucket
constexpr int NBUK = (NN + BNOD - 1) / BNOD;    // 245
constexpr int NBLK = 1000;                      // partition blocks
constexpr int EPB  = NE / NBLK;                 // 8000 edges / block
constexpr int QPB  = EPB / 4;                   // 2000 int4 / block
constexpr int HTOT = NBUK * NBLK;               // 245000

constexpr int SCH = 2048;                       // scan chunk (256 thr x 8)
constexpr int NSB = (HTOT + SCH - 1) / SCH;     // 120

// ---- build: bucket histogram (LDS-private, no global atomics) --------------

__global__ __launch_bounds__(256) void k_bhist(const int* __restrict__ dst,
                                               int* __restrict__ bhist) {
  __shared__ int hist[NBUK];
  int b = blockIdx.x, t = threadIdx.x;
  for (int h = t; h < NBUK; h += 256) hist[h] = 0;
  __syncthreads();
  const int4* d4p = (const int4*)dst + (size_t)b * QPB;
  for (int i = t; i < QPB; i += 256) {
    int4 d = d4p[i];
    atomicAdd(&hist[d.x >> BSH], 1);
    atomicAdd(&hist[d.y >> BSH], 1);
    atomicAdd(&hist[d.z >> BSH], 1);
    atomicAdd(&hist[d.w >> BSH], 1);
  }
  __syncthreads();
  for (int h = t; h < NBUK; h += 256) bhist[h * NBLK + b] = hist[h];  // bucket-major
}

// ---- build: scan of bucket-major blockHist (245k ints) ---------------------

__global__ __launch_bounds__(256) void k_scan_partial(const int* __restrict__ cnt,
                                                      int* __restrict__ partials) {
  __shared__ int sm[256];
  int b = blockIdx.x, t = threadIdx.x;
  int base = b * SCH + t * 8;
  int s = 0;
#pragma unroll
  for (int j = 0; j < 8; ++j) {
    int i = base + j;
    s += (i < HTOT) ? cnt[i] : 0;
  }
  sm[t] = s;
  __syncthreads();
  for (int off = 128; off > 0; off >>= 1) {
    if (t < off) sm[t] += sm[t + off];
    __syncthreads();
  }
  if (t == 0) partials[b] = sm[0];
}

__global__ __launch_bounds__(256) void k_scan_mid(int* __restrict__ partials) {
  __shared__ int sm[256];
  int t = threadIdx.x;
  int v = (t < NSB) ? partials[t] : 0;
  sm[t] = v;
  __syncthreads();
  for (int off = 1; off < 256; off <<= 1) {
    int x = (t >= off) ? sm[t - off] : 0;
    __syncthreads();
    sm[t] += x;
    __syncthreads();
  }
  if (t < NSB) partials[t] = sm[t] - v;  // exclusive
}

// in-place: each element read then written by the same thread only
__global__ __launch_bounds__(256) void k_scan_down(int* __restrict__ data,
                                                   const int* __restrict__ partials) {
  __shared__ int sm[256];
  int b = blockIdx.x, t = threadIdx.x;
  int base = b * SCH + t * 8;
  int v[8];
  int s = 0;
#pragma unroll
  for (int j = 0; j < 8; ++j) {
    int i = base + j;
    v[j] = (i < HTOT) ? data[i] : 0;
    s += v[j];
  }
  sm[t] = s;
  __syncthreads();
  for (int off = 1; off < 256; off <<= 1) {
    int x = (t >= off) ? sm[t - off] : 0;
    __syncthreads();
    sm[t] += x;
    __syncthreads();
  }
  int run = partials[b] + (sm[t] - s);
#pragma unroll
  for (int j = 0; j < 8; ++j) {
    int i = base + j;
    if (i < HTOT) data[i] = run;
    run += v[j];
  }
}

// ---- build: permute edges into buckets (LDS cursors, contiguous runs) ------

__global__ __launch_bounds__(256) void k_bscatter(const int* __restrict__ src,
                                                  const int* __restrict__ dst,
                                                  const int* __restrict__ off,
                                                  unsigned int* __restrict__ col) {
  __shared__ int cur[NBUK];
  int b = blockIdx.x, t = threadIdx.x;
  for (int h = t; h < NBUK; h += 256) cur[h] = off[h * NBLK + b];
  __syncthreads();
  const int4* s4p = (const int4*)src + (size_t)b * QPB;
  const int4* d4p = (const int4*)dst + (size_t)b * QPB;
  for (int i = t; i < QPB; i += 256) {
    int4 s = s4p[i];
    int4 d = d4p[i];
    int p0 = atomicAdd(&cur[d.x >> BSH], 1);
    col[p0] = ((unsigned)(d.x & (BNOD - 1)) << 19) | (unsigned)s.x;
    int p1 = atomicAdd(&cur[d.y >> BSH], 1);
    col[p1] = ((unsigned)(d.y & (BNOD - 1)) << 19) | (unsigned)s.y;
    int p2 = atomicAdd(&cur[d.z >> BSH], 1);
    col[p2] = ((unsigned)(d.z & (BNOD - 1)) << 19) | (unsigned)s.z;
    int p3 = atomicAdd(&cur[d.w >> BSH], 1);
    col[p3] = ((unsigned)(d.w & (BNOD - 1)) << 19) | (unsigned)s.w;
  }
}

// ---- deg + dis + layer-0 gather table, per bucket (LDS int hist) -----------

__global__ __launch_bounds__(1024) void k_bdeg(const unsigned int* __restrict__ col,
                                               const int* __restrict__ off,
                                               const float2* __restrict__ X,
                                               float* __restrict__ dis,
                                               float4* __restrict__ g0) {
  __shared__ int hist[BNOD];
  int b = blockIdx.x, t = threadIdx.x;
  hist[t] = 0;
  hist[t + 1024] = 0;
  __syncthreads();
  int e0 = off[b * NBLK];
  int e1 = (b + 1 < NBUK) ? off[(b + 1) * NBLK] : NE;
  for (int e = e0 + t; e < e1; e += 1024) {
    atomicAdd(&hist[col[e] >> 19], 1);
  }
  __syncthreads();
  int base = b << BSH;
#pragma unroll
  for (int j = 0; j < 2; ++j) {
    int li = t + j * 1024;
    int i = base + li;
    if (i < NN) {
      float d = 1.0f / sqrtf((float)hist[li] + 1.0f);
      dis[i] = d;
      float2 x = X[i];
      g0[i] = make_float4(d * x.x, d * x.y, d, 0.f);
    }
  }
}

// ---- layer 0: LDS accumulate (x,y,dis) + folded step-emb + 2x10 dense ------

__global__ __launch_bounds__(1024) void k_blayer0(const unsigned int* __restrict__ col,
                                                  const int* __restrict__ off,
                                                  const float4* __restrict__ g0,
                                                  const float2* __restrict__ X,
                                                  const float* __restrict__ dis,
                                                  const float* __restrict__ W0,
                                                  const float* __restrict__ b0,
                                                  const float* __restrict__ step_emb,
                                                  const int* __restrict__ step_index,
                                                  float2* __restrict__ xs_out) {
  __shared__ float acc[BNOD * 3];
  int b = blockIdx.x, t = threadIdx.x;
  for (int j = t; j < BNOD * 3; j += 1024) acc[j] = 0.f;
  __syncthreads();
  int e0 = off[b * NBLK];
  int e1 = (b + 1 < NBUK) ? off[(b + 1) * NBLK] : NE;
  for (int e = e0 + t; e < e1; e += 1024) {
    unsigned p = col[e];
    int s = p & 0x7FFFF;
    int ld = p >> 19;
    float4 g = g0[s];
    atomicAdd(&acc[ld * 3 + 0], g.x);
    atomicAdd(&acc[ld * 3 + 1], g.y);
    atomicAdd(&acc[ld * 3 + 2], g.z);
  }
  __syncthreads();
  // uniform constants: s-columns of W0 folded (s constant across nodes)
  const float* sv = step_emb + step_index[0] * STEP_DIM;
  float c0[2], c1[2];
#pragma unroll
  for (int o = 0; o < 2; ++o) {
    float a0 = b0[o] + b0[2 + o];
    float a1 = 0.f;
#pragma unroll
    for (int j = 0; j < STEP_DIM; ++j) {
      a0 += sv[j] * W0[(2 + j) * 2 + o];
      a1 += sv[j] * W0[20 + (2 + j) * 2 + o];
    }
    c0[o] = a0;
    c1[o] = a1;
  }
  int base = b << BSH;
#pragma unroll
  for (int j = 0; j < 2; ++j) {
    int li = t + j * 1024;
    int i = base + li;
    if (i < NN) {
      float d = dis[i], d2 = d * d;
      float2 x = X[i];
      float sx = acc[li * 3 + 0], sy = acc[li * 3 + 1], sd = acc[li * 3 + 2];
      float px = d * sx + d2 * x.x;
      float py = d * sy + d2 * x.y;
      float rowsum = d * sd + d2;
      float h0 = c0[0] + rowsum * c1[0] + x.x * W0[0] + x.y * W0[2] + px * W0[20] + py * W0[22];
      float h1 = c0[1] + rowsum * c1[1] + x.x * W0[1] + x.y * W0[3] + px * W0[21] + py * W0[23];
      h0 = fmaxf(h0, 0.f);
      h1 = fmaxf(h1, 0.f);
      xs_out[i] = make_float2(d * h0, d * h1);
    }
  }
}

// ---- layers 1..7: LDS accumulate + 2x2 dense + relu ------------------------
// xs holds dis*x; self term dis^2*x = dis*xs; x = xs/dis.

__global__ __launch_bounds__(1024) void k_blayer(const unsigned int* __restrict__ col,
                                                 const int* __restrict__ off,
                                                 const float* __restrict__ dis,
                                                 const float2* __restrict__ xs_in,
                                                 const float* __restrict__ W,
                                                 const float* __restrict__ bb,
                                                 float2* __restrict__ xs_out,
                                                 float2* __restrict__ out,
                                                 int last) {
  __shared__ float acc[BNOD * 2];
  int b = blockIdx.x, t = threadIdx.x;
  for (int j = t; j < BNOD * 2; j += 1024) acc[j] = 0.f;
  __syncthreads();
  int e0 = off[b * NBLK];
  int e1 = (b + 1 < NBUK) ? off[(b + 1) * NBLK] : NE;
  for (int e = e0 + t; e < e1; e += 1024) {
    unsigned p = col[e];
    int s = p & 0x7FFFF;
    int ld = p >> 19;
    float2 v = xs_in[s];
    atomicAdd(&acc[ld * 2 + 0], v.x);
    atomicAdd(&acc[ld * 2 + 1], v.y);
  }
  __syncthreads();
  int base = b << BSH;
#pragma unroll
  for (int j = 0; j < 2; ++j) {
    int li = t + j * 1024;
    int i = base + li;
    if (i < NN) {
      float d = dis[i];
      float2 xsv = xs_in[i];
      float inv = 1.0f / d;
      float xx = xsv.x * inv, xy = xsv.y * inv;
      float px = d * (acc[li * 2 + 0] + xsv.x);
      float py = d * (acc[li * 2 + 1] + xsv.y);
      float h0 = bb[0] + bb[2] + xx * W[0] + xy * W[2] + px * W[4] + py * W[6];
      float h1 = bb[1] + bb[3] + xx * W[1] + xy * W[3] + px * W[5] + py * W[7];
      h0 = fmaxf(h0, 0.f);
      h1 = fmaxf(h1, 0.f);
      if (last) {
        out[i] = make_float2(h0, h1);
      } else {
        xs_out[i] = make_float2(d * h0, d * h1);
      }
    }
  }
}

// ---- driver ----------------------------------------------------------------

extern "C" void kernel_launch(void* const* d_in, const int* in_sizes, int n_in,
                              void* d_out, int out_size, void* d_ws, size_t ws_size,
                              hipStream_t stream) {
  const float2* X        = (const float2*)d_in[0];
  const int*    edge     = (const int*)d_in[1];
  const int*    src      = edge;
  const int*    dstp     = edge + NE;
  const int*    step_idx = (const int*)d_in[2];
  const float*  step_emb = (const float*)d_in[3];
  const float*  W0       = (const float*)d_in[4];
  const float*  b0       = (const float*)d_in[5];
  const float*  Wh       = (const float*)d_in[6];
  const float*  bbias    = (const float*)d_in[7];

  // ws ints: [col: NE][bhist: HTOT][partials: 512][g0: 4N f][xsA: 2N f][xsB: 2N f][dis: N f]
  int*      ip       = (int*)d_ws;
  unsigned* col      = (unsigned*)ip;
  int*      bhist    = ip + NE;
  int*      partials = ip + NE + HTOT;
  size_t    off2     = (size_t)NE + HTOT + 512;        // multiple of 4 -> 16B aligned
  float4*   g0       = (float4*)(ip + off2);
  float2*   xsA      = (float2*)(ip + off2 + 4 * (size_t)NN);
  float2*   xsB      = (float2*)(ip + off2 + 6 * (size_t)NN);
  float*    dis      = (float*)(ip + off2 + 8 * (size_t)NN);

  k_bhist<<<NBLK, 256, 0, stream>>>(dstp, bhist);
  k_scan_partial<<<NSB, 256, 0, stream>>>(bhist, partials);
  k_scan_mid<<<1, 256, 0, stream>>>(partials);
  k_scan_down<<<NSB, 256, 0, stream>>>(bhist, partials);
  k_bscatter<<<NBLK, 256, 0, stream>>>(src, dstp, bhist, col);
  k_bdeg<<<NBUK, 1024, 0, stream>>>(col, bhist, X, dis, g0);

  k_blayer0<<<NBUK, 1024, 0, stream>>>(col, bhist, g0, X, dis, W0, b0,
                                       step_emb, step_idx, xsB);
  float2* cur = xsB;
  float2* nxt = xsA;
  for (int l = 0; l < HIDM1; ++l) {
    k_blayer<<<NBUK, 1024, 0, stream>>>(col, bhist, dis, cur, Wh + l * 8,
                                        bbias + l * 4, nxt, (float2*)d_out,
                                        l == HIDM1 - 1 ? 1 : 0);
    float2* tmp = cur;
    cur = nxt;
    nxt = tmp;
  }
}